// Round 3
// baseline (230.734 us; speedup 1.0000x reference)
//
#include <hip/hip_runtime.h>

// CenterLoss: loss = (1/B) * sum_j [ sum_{i: l_i=j} ||f_i - c_j||^2 / (n_j * D) ]
//           = (1/B) * sum_i d_i / (n_{l_i} * D)        (equivalent form, used here)
// B=65536, D=512, C=1000, fp32 in / fp32 scalar out. Memory-bound:
// 128 MiB features + 2 MiB centers + 0.25 MiB labels -> roofline ~21 us @ 6.3 TB/s.
//
// v4: attribution experiment + de-risk. v1..v3 all carried global fp32 atomics
// and a memset; counters show the timed window is dominated by ~77.5us 512MiB
// harness poison fills, so our share is unattributable. v4 removes ALL global
// atomics and ALL memsets: dist stores per-sample d_i (256KB coalesced), counts
// come from a block-private LDS histogram spilled per block (fully overwritten
// buffers -> no zeroing), final = single-block gather-reduce. Our predicted
// total ~30us. If dur_us stays ~200, the floor is the harness, not us.

#define WAVE 64
#define HPAD 1024           // padded class stride for histogram/invcnt buffers

// K1: one wave per sample. Lanes cooperatively load the sample row + its center
// row as float4 (coalesced, 16B/lane), butterfly-reduce the squared distance,
// lane 0 stores d_i. No atomics.
__global__ __launch_bounds__(256) void center_dist_kernel(
    const float* __restrict__ features,   // [batch, feat]
    const float* __restrict__ centers,    // [nclass, feat]
    const int*   __restrict__ labels,     // [batch]
    float* __restrict__ dvals,            // [batch]
    int batch, int feat)
{
    const int wave_in_block = threadIdx.x >> 6;
    const int lane          = threadIdx.x & 63;
    const int sample        = blockIdx.x * 4 + wave_in_block;
    if (sample >= batch) return;

    const int label = labels[sample];     // longest dependent chain: issue first

    const float4* __restrict__ f4 =
        (const float4*)(features + (size_t)sample * feat);
    const float4* __restrict__ c4 =
        (const float4*)(centers + (size_t)label * feat);

    float acc = 0.0f;
    const int n4 = feat >> 2;             // 128 for feat=512
#pragma unroll 2
    for (int idx = lane; idx < n4; idx += WAVE) {
        float4 fv = f4[idx];
        float4 cv = c4[idx];
        float dx = fv.x - cv.x;
        float dy = fv.y - cv.y;
        float dz = fv.z - cv.z;
        float dw = fv.w - cv.w;
        acc += dx * dx + dy * dy;
        acc += dz * dz + dw * dw;
    }

#pragma unroll
    for (int off = 32; off > 0; off >>= 1)
        acc += __shfl_down(acc, off, WAVE);

    if (lane == 0) dvals[sample] = acc;
}

// K2: per-block LDS histogram of 1024 labels, spilled densely (no global
// atomics, buffer fully overwritten -> no zeroing needed).
__global__ __launch_bounds__(256) void hist_kernel(
    const int* __restrict__ labels,       // [batch]
    unsigned int* __restrict__ hist,      // [nblocks][HPAD]
    int batch, int nclass)
{
    __shared__ unsigned int h[HPAD];
    for (int j = threadIdx.x; j < HPAD; j += 256) h[j] = 0u;
    __syncthreads();

    const int base = blockIdx.x * 1024;
    for (int k = threadIdx.x; k < 1024; k += 256) {
        const int i = base + k;
        if (i < batch) atomicAdd(&h[labels[i]], 1u);   // LDS atomic: cheap
    }
    __syncthreads();

    unsigned int* __restrict__ out = hist + (size_t)blockIdx.x * HPAD;
    for (int j = threadIdx.x; j < nclass; j += 256) out[j] = h[j];
}

// K3: collapse per-block histograms -> invcnt[j] = n_j>0 ? 1/(n_j*feat) : 0.
// Single block, 1024 threads, coalesced over j (stride-HPAD over blocks).
__global__ __launch_bounds__(1024) void counts_kernel(
    const unsigned int* __restrict__ hist, // [nblocks][HPAD]
    float* __restrict__ invcnt,            // [HPAD]
    int nclass, int feat, int nblocks)
{
    for (int j = threadIdx.x; j < nclass; j += 1024) {
        unsigned int n = 0;
#pragma unroll 4
        for (int b = 0; b < nblocks; ++b)
            n += hist[(size_t)b * HPAD + j];
        invcnt[j] = (n > 0u) ? 1.0f / ((float)n * (float)feat) : 0.0f;
    }
}

// K4: loss = (1/B) * sum_i d_i * invcnt[l_i]. Single block, 1024 threads;
// d and labels are coalesced streams (256B/wave-instr), invcnt is a 4KB
// L1-resident gather.
__global__ __launch_bounds__(1024) void final_kernel(
    const float* __restrict__ dvals,      // [batch]
    const int*   __restrict__ labels,     // [batch]
    const float* __restrict__ invcnt,     // [HPAD]
    float* __restrict__ out,
    int batch)
{
    float acc = 0.0f;
    for (int i = threadIdx.x; i < batch; i += 1024)
        acc += dvals[i] * invcnt[labels[i]];

#pragma unroll
    for (int off = 32; off > 0; off >>= 1)
        acc += __shfl_down(acc, off, WAVE);

    __shared__ float warp_part[16];
    const int lane = threadIdx.x & 63;
    const int wid  = threadIdx.x >> 6;
    if (lane == 0) warp_part[wid] = acc;
    __syncthreads();

    if (threadIdx.x < WAVE) {
        float v = (threadIdx.x < 16) ? warp_part[threadIdx.x] : 0.0f;
#pragma unroll
        for (int off = 8; off > 0; off >>= 1)
            v += __shfl_down(v, off, WAVE);
        if (threadIdx.x == 0) out[0] = v / (float)batch;
    }
}

extern "C" void kernel_launch(void* const* d_in, const int* in_sizes, int n_in,
                              void* d_out, int out_size, void* d_ws, size_t ws_size,
                              hipStream_t stream) {
    const float* features = (const float*)d_in[0];
    const float* centers  = (const float*)d_in[1];
    const int*   labels   = (const int*)d_in[2];

    const int batch  = in_sizes[2];                 // 65536
    const int feat   = in_sizes[0] / batch;         // 512
    const int nclass = in_sizes[1] / feat;          // 1000

    const int nblocks_h = (batch + 1023) / 1024;    // 64

    // Workspace layout (all fully overwritten -> no memset):
    //   dvals  [batch]            f32   256 KB
    //   hist   [nblocks_h][HPAD]  u32   256 KB
    //   invcnt [HPAD]             f32     4 KB
    float*        dvals  = (float*)d_ws;
    unsigned int* hist   = (unsigned int*)(dvals + batch);
    float*        invcnt = (float*)(hist + (size_t)nblocks_h * HPAD);

    center_dist_kernel<<<(batch + 3) / 4, 256, 0, stream>>>(
        features, centers, labels, dvals, batch, feat);

    hist_kernel<<<nblocks_h, 256, 0, stream>>>(labels, hist, batch, nclass);

    counts_kernel<<<1, 1024, 0, stream>>>(hist, invcnt, nclass, feat, nblocks_h);

    final_kernel<<<1, 1024, 0, stream>>>(dvals, labels, invcnt,
                                         (float*)d_out, batch);
}

// Round 4
// 195.061 us; speedup vs baseline: 1.1829x; 1.1829x over previous
//
#include <hip/hip_runtime.h>

// CenterLoss: loss = (1/B) * sum_j [ sum_{i: l_i=j} ||f_i - c_j||^2 / (n_j * D) ]
//           = (1/B) * sum_i d_i / (n_{l_i} * D)        (per-sample form, used here)
// B=65536, D=512, C=1000, fp32 in / fp32 scalar out. Memory-bound:
// 128 MiB features + 2 MiB centers + 0.25 MiB labels -> roofline ~21 us @ 6.3 TB/s.
//
// v5: v2/v4 post-mortems show the controllable cost is single-CU latency-bound
// TAIL work, not atomics. v5 keeps v4's no-atomics/no-memset property but
// collapses the tail: (1) histogram spilled TRANSPOSED histT[class][64] so a
// wave fetches its label's count as ONE coalesced 256B read (lane l reads
// column l) and reduces it in the same butterfly as the distance; (2) the
// 1/(n*D) scale is fused into the dist kernel (no dvals round-trip, no invcnt
// kernel); (3) tail = one 64KB coalesced reduce. 3 dispatches total.

#define WAVE 64
#define NCOL 64             // histogram columns == wavefront size (fixed)
#define HPAD 1024           // padded class count (nclass=1000 <= HPAD)

// K1: 64 blocks; block b LDS-histograms its slab of labels, spills column b of
// the transposed histogram. Buffer fully overwritten -> no zeroing needed.
__global__ __launch_bounds__(256) void hist_kernel(
    const int* __restrict__ labels,       // [batch]
    unsigned int* __restrict__ histT,     // [HPAD][NCOL]
    int batch, int nclass, int slab)
{
    __shared__ unsigned int h[HPAD];
    for (int j = threadIdx.x; j < HPAD; j += 256) h[j] = 0u;
    __syncthreads();

    const int b  = blockIdx.x;            // 0..NCOL-1
    const int lo = b * slab;
    int hi = lo + slab; if (hi > batch) hi = batch;
    for (int i = lo + threadIdx.x; i < hi; i += 256)
        atomicAdd(&h[labels[i]], 1u);     // LDS atomic: cheap
    __syncthreads();

    for (int j = threadIdx.x; j < nclass; j += 256)
        histT[(size_t)j * NCOL + b] = h[j];
}

// K2: one wave per sample. Lanes cooperatively load the sample row + its
// center row as float4 (coalesced, 16B/lane); lane l also loads histT[label][l]
// (one coalesced 256B read per wave). Butterfly-reduces distance and count
// together, lane 0 forms d/(n*feat); block combines 4 waves -> 1 partial.
__global__ __launch_bounds__(256) void center_dist_kernel(
    const float* __restrict__ features,   // [batch, feat]
    const float* __restrict__ centers,    // [nclass, feat]
    const int*   __restrict__ labels,     // [batch]
    const unsigned int* __restrict__ histT, // [HPAD][NCOL]
    float* __restrict__ partials,         // [gridDim.x]
    int batch, int feat)
{
    const int wib    = threadIdx.x >> 6;  // 0..3
    const int lane   = threadIdx.x & 63;
    const int sample = blockIdx.x * 4 + wib;

    __shared__ float wsum[4];
    float term = 0.0f;

    if (sample < batch) {
        const int label = labels[sample];

        // issue the count load early; it's L2-hot (256KB table)
        unsigned int nl = histT[(size_t)label * NCOL + lane];

        const float4* __restrict__ f4 =
            (const float4*)(features + (size_t)sample * feat);
        const float4* __restrict__ c4 =
            (const float4*)(centers + (size_t)label * feat);

        float acc = 0.0f;
        const int n4 = feat >> 2;         // 128 for feat=512
#pragma unroll 2
        for (int idx = lane; idx < n4; idx += WAVE) {
            float4 fv = f4[idx];
            float4 cv = c4[idx];
            float dx = fv.x - cv.x;
            float dy = fv.y - cv.y;
            float dz = fv.z - cv.z;
            float dw = fv.w - cv.w;
            acc += dx * dx + dy * dy;
            acc += dz * dz + dw * dw;
        }

        int n = (int)nl;
#pragma unroll
        for (int off = 32; off > 0; off >>= 1) {
            acc += __shfl_down(acc, off, WAVE);
            n   += __shfl_down(n,   off, WAVE);
        }
        // lane 0 holds full sums; n >= 1 guaranteed (this sample has label l)
        term = acc / ((float)n * (float)feat);
    }

    if (lane == 0) wsum[wib] = term;
    __syncthreads();
    if (threadIdx.x == 0)
        partials[blockIdx.x] = wsum[0] + wsum[1] + wsum[2] + wsum[3];
}

// K3: single block, 1024 threads: reduce the 16384 block partials (64 KB,
// coalesced) -> loss scalar.
__global__ __launch_bounds__(1024) void reduce_kernel(
    const float* __restrict__ partials, float* __restrict__ out,
    int n, int batch)
{
    float acc = 0.0f;
#pragma unroll 4
    for (int i = threadIdx.x; i < n; i += 1024)
        acc += partials[i];

#pragma unroll
    for (int off = 32; off > 0; off >>= 1)
        acc += __shfl_down(acc, off, WAVE);

    __shared__ float warp_part[16];
    const int lane = threadIdx.x & 63;
    const int wid  = threadIdx.x >> 6;
    if (lane == 0) warp_part[wid] = acc;
    __syncthreads();

    if (threadIdx.x < WAVE) {
        float v = (threadIdx.x < 16) ? warp_part[threadIdx.x] : 0.0f;
#pragma unroll
        for (int off = 8; off > 0; off >>= 1)
            v += __shfl_down(v, off, WAVE);
        if (threadIdx.x == 0) out[0] = v / (float)batch;
    }
}

extern "C" void kernel_launch(void* const* d_in, const int* in_sizes, int n_in,
                              void* d_out, int out_size, void* d_ws, size_t ws_size,
                              hipStream_t stream) {
    const float* features = (const float*)d_in[0];
    const float* centers  = (const float*)d_in[1];
    const int*   labels   = (const int*)d_in[2];

    const int batch  = in_sizes[2];                 // 65536
    const int feat   = in_sizes[0] / batch;         // 512
    const int nclass = in_sizes[1] / feat;          // 1000

    const int slab        = (batch + NCOL - 1) / NCOL;   // 1024
    const int dist_blocks = (batch + 3) / 4;             // 16384

    // Workspace layout (all fully overwritten -> no memset):
    //   histT    [HPAD][NCOL] u32   256 KB
    //   partials [dist_blocks] f32   64 KB
    unsigned int* histT    = (unsigned int*)d_ws;
    float*        partials = (float*)(histT + (size_t)HPAD * NCOL);

    hist_kernel<<<NCOL, 256, 0, stream>>>(labels, histT, batch, nclass, slab);

    center_dist_kernel<<<dist_blocks, 256, 0, stream>>>(
        features, centers, labels, histT, partials, batch, feat);

    reduce_kernel<<<1, 1024, 0, stream>>>(partials, (float*)d_out,
                                          dist_blocks, batch);
}